// Round 4
// baseline (339.438 us; speedup 1.0000x reference)
//
#include <hip/hip_runtime.h>
#include <math.h>

#define B_  16
#define C_  64
#define H_  192
#define W_  192
#define R_  64
#define HW_ (H_*W_)            // 36864
#define HCH 6                  // h rows per main block: 192/6=32 chunks, 16*32*3=1536 blocks = 6/CU

// ---------------- ws layout (floats) ----------------
#define OFF_CP  0
#define OFF_HP  1024
#define OFF_WP  4096
#define OFF_MC  7168           // Mc stored as bf16: 16*64*64 ushorts = 32768 floats of space
#define OFF_HWS 72704
#define OFF_WWS 269312

typedef __attribute__((ext_vector_type(8))) short bf16x8;
typedef __attribute__((ext_vector_type(4))) float f32x4;

static __device__ __forceinline__ short f2bf(float f) {
    unsigned u = __float_as_uint(f);
    unsigned r = u + 0x7fffu + ((u >> 16) & 1u);   // RNE
    return (short)(r >> 16);
}

__global__ __launch_bounds__(256) void zero_kernel(float* p, int n) {
    int i = blockIdx.x * 256 + threadIdx.x;
    if (i < n) p[i] = 0.f;
}

// One block per (b,c). 4 waves; wave wv owns rows [48*wv, 48*wv+48).
// (R1-proven config: float4 loads, unroll 2.)
__global__ __launch_bounds__(256) void pool_kernel(const float* __restrict__ X,
                                                   float* __restrict__ cp,
                                                   float* __restrict__ hp,
                                                   float* __restrict__ wp) {
    int b = blockIdx.x >> 6;
    int c = blockIdx.x & 63;
    int tid = threadIdx.x;
    int wv = tid >> 6, lane = tid & 63;
    int sub = lane >> 4;           // row offset within 4-row group
    int li  = lane & 15;           // position within row
    const float* base = X + (size_t)(b * C_ + c) * HW_ + (size_t)(wv * 48) * W_;

    __shared__ float rowsum[H_];
    __shared__ f32x4 colpart4[4][48];   // [wave][w/4]
    __shared__ float cpart[3];

    f32x4 cacc0 = {0.f,0.f,0.f,0.f}, cacc1 = {0.f,0.f,0.f,0.f}, cacc2 = {0.f,0.f,0.f,0.f};

    #pragma unroll 2
    for (int hh = 0; hh < 48; hh += 4) {
        const float* rp = base + (size_t)(hh + sub) * W_;
        f32x4 x0 = *(const f32x4*)(rp + 4 * li);
        f32x4 x1 = *(const f32x4*)(rp + 4 * (li + 16));
        f32x4 x2 = *(const f32x4*)(rp + 4 * (li + 32));
        cacc0 += x0; cacc1 += x1; cacc2 += x2;
        float s = (x0[0]+x0[1]+x0[2]+x0[3]) + (x1[0]+x1[1]+x1[2]+x1[3])
                + (x2[0]+x2[1]+x2[2]+x2[3]);
        // reduce within the 16-lane group (each group = one row)
        s += __shfl_down(s, 8);
        s += __shfl_down(s, 4);
        s += __shfl_down(s, 2);
        s += __shfl_down(s, 1);
        if (li == 0) rowsum[wv * 48 + hh + sub] = s;
    }
    // reduce col accumulators across the 4 sub-groups (lanes l, l+16, l+32, l+48)
    #pragma unroll
    for (int comp = 0; comp < 4; ++comp) {
        float t0 = cacc0[comp]; t0 += __shfl_down(t0, 16); t0 += __shfl_down(t0, 32); cacc0[comp] = t0;
        float t1 = cacc1[comp]; t1 += __shfl_down(t1, 16); t1 += __shfl_down(t1, 32); cacc1[comp] = t1;
        float t2 = cacc2[comp]; t2 += __shfl_down(t2, 16); t2 += __shfl_down(t2, 32); cacc2[comp] = t2;
    }
    if (lane < 16) {
        colpart4[wv][li]      = cacc0;
        colpart4[wv][li + 16] = cacc1;
        colpart4[wv][li + 32] = cacc2;
    }
    __syncthreads();

    const float inv_cw = 1.0f / 12288.0f;   // 1/(C*W) == 1/(C*H)
    if (tid < 192) {
        const float* cpf = (const float*)colpart4;
        float colv = cpf[tid] + cpf[192 + tid] + cpf[384 + tid] + cpf[576 + tid];
        atomicAdd(&wp[b * W_ + tid], colv * inv_cw);
        float rv = rowsum[tid];
        atomicAdd(&hp[b * H_ + tid], rv * inv_cw);
        float s = rv;
        s += __shfl_down(s, 32);
        s += __shfl_down(s, 16);
        s += __shfl_down(s, 8);
        s += __shfl_down(s, 4);
        s += __shfl_down(s, 2);
        s += __shfl_down(s, 1);
        if ((tid & 63) == 0) cpart[tid >> 6] = s;
    }
    __syncthreads();
    if (tid == 0) cp[b * C_ + c] = (cpart[0] + cpart[1] + cpart[2]) * (1.0f / (float)HW_);
}

// All three affine+sigmoid maps in ONE launch, partitioned by blockIdx:
//   [0,256)      : Mc [b][c][r] = bf16(p[r]*sigmoid(Wc.cp+bc))   D=K=64  (bf16 out!)
//   [256,1024)   : Hws[b][h][r] = sigmoid(Wh.hp+bh)              D=K=192
//   [1024,1792)  : Wws[b][w][r] = sigmoid(Ww.wp+bw)              D=K=192
// Mc is pre-converted to bf16 here (same RNE conversion main_kernel used to do
// per-block) -> main loads B-fragments directly, numerically identical.
__global__ __launch_bounds__(256) void affine_all_kernel(
        const float* __restrict__ Wc, const float* __restrict__ bc,
        const float* __restrict__ Wh, const float* __restrict__ bh,
        const float* __restrict__ Ww, const float* __restrict__ bw,
        const float* __restrict__ cp, const float* __restrict__ hp,
        const float* __restrict__ wp, const float* __restrict__ p,
        unsigned short* __restrict__ McBf, float* __restrict__ Hws,
        float* __restrict__ Wws) {
    __shared__ float pl[16 * 193];
    int blk = blockIdx.x;
    const float *Wsrc, *bias, *pool, *pmul;
    float* outp = nullptr;
    bool isMc = false;
    int D, K;
    if (blk < 256) {
        Wsrc = Wc; bias = bc; pool = cp; pmul = p; isMc = true; D = C_; K = C_;
    } else if (blk < 1024) {
        blk -= 256;
        Wsrc = Wh; bias = bh; pool = hp; pmul = nullptr; outp = Hws; D = H_; K = H_;
    } else {
        blk -= 1024;
        Wsrc = Ww; bias = bw; pool = wp; pmul = nullptr; outp = Wws; D = W_; K = W_;
    }

    int tid = threadIdx.x;
    for (int i = tid; i < 16 * K; i += 256) {
        int bb = i / K, kk = i - bb * K;
        pl[bb * (K + 1) + kk] = pool[i];
    }
    __syncthreads();

    int b  = tid & 15;
    int rl = tid >> 4;
    int row = blk * 16 + rl;
    int r = row / D, d = row - r * D;

    const float4* w4 = (const float4*)(Wsrc + (size_t)row * K);
    const float*  pb = &pl[b * (K + 1)];
    float acc = 0.f;
    #pragma unroll 8
    for (int k4 = 0; k4 < (K >> 2); ++k4) {
        float4 wv = w4[k4];
        int k = k4 << 2;
        acc += wv.x * pb[k] + wv.y * pb[k + 1] + wv.z * pb[k + 2] + wv.w * pb[k + 3];
    }
    acc += bias[row];
    float sgm = 1.0f / (1.0f + __expf(-acc));
    if (isMc) {
        sgm *= pmul[r];
        McBf[(size_t)b * (C_ * R_) + (size_t)d * R_ + r] = (unsigned short)f2bf(sgm);
    } else {
        outp[(size_t)b * (D * R_) + (size_t)d * R_ + r] = sgm;
    }
}

// One block per (b, 6-row h chunk, 64-wide w strip): grid 16*32*3 = 1536.
// __launch_bounds__(256,4) caps VGPR at 128 -> 4 blocks/CU RESIDENT (16 waves/CU,
// +33% TLP vs the 3-wave/SIMD R1-R3 builds; R2's HCH=6 failed without this cap).
// B-fragments now load directly as bf16 (converted upstream in affine) -> per-
// block setup is 12 loads, no cvt; register diet funds the occupancy bump.
__global__ __launch_bounds__(256, 4) void main_kernel(const float* __restrict__ X,
                                                      const unsigned short* __restrict__ McBf,
                                                      const float* __restrict__ Hws,
                                                      const float* __restrict__ Wws,
                                                      float* __restrict__ out) {
    int blk = blockIdx.x;
    int b = blk / 96;                  // 32 h-chunks * 3 w-strips
    int rem = blk - b * 96;
    int hc = rem / 3;
    int w0 = (rem - hc * 3) * 64;
    int h0 = hc * HCH;
    int tid = threadIdx.x;
    int wv = tid >> 6, lane = tid & 63;
    int m = lane & 15, quad = lane >> 4;

    const short* McB = (const short*)McBf + (size_t)b * (C_ * R_);
    const float* HvB = Hws + (size_t)b * H_ * R_;
    const float* WwB = Wws + ((size_t)b * W_ + w0) * R_;

    // ---- B fragments: direct bf16 16B loads, once per block ----
    bf16x8 bfrag[4][2];
    #pragma unroll
    for (int ct = 0; ct < 4; ++ct) {
        #pragma unroll
        for (int ks = 0; ks < 2; ++ks)
            bfrag[ct][ks] = *(const bf16x8*)(McB + (size_t)(ct * 16 + m) * R_ + ks * 32 + quad * 8);
    }

    // ---- Ww per-lane weights (A row = w = wv*16+m), fixed across h ----
    float4 wwf[2][2];
    #pragma unroll
    for (int ks = 0; ks < 2; ++ks) {
        const float4* wp4 = (const float4*)(WwB + (size_t)(wv * 16 + m) * R_ + ks * 32 + quad * 8);
        wwf[ks][0] = wp4[0]; wwf[ks][1] = wp4[1];
    }

    int wbase = w0 + wv * 16 + quad * 4;
    const float* Xb = X   + (size_t)b * C_ * HW_;
    float*       Ob = out + (size_t)b * C_ * HW_;

    // depth-1 prefetch (depth-2 measured neutral in R3; reclaim the 16 VGPRs)
    float4 xv[2][4];
    {
        size_t pix0 = (size_t)h0 * W_ + wbase;
        #pragma unroll
        for (int ct = 0; ct < 4; ++ct)
            xv[0][ct] = *(const float4*)(Xb + (size_t)(ct * 16 + m) * HW_ + pix0);
    }

    #pragma unroll
    for (int hi = 0; hi < HCH; ++hi) {
        const int cur = hi & 1;
        const int nxt = cur ^ 1;
        int h = h0 + hi;

        // prefetch X for h+1 first
        if (hi + 1 < HCH) {
            size_t pixn = (size_t)(h + 1) * W_ + wbase;
            #pragma unroll
            for (int ct = 0; ct < 4; ++ct)
                xv[nxt][ct] = *(const float4*)(Xb + (size_t)(ct * 16 + m) * HW_ + pixn);
        }

        // Hv for this h (broadcast-ish: 4 distinct 16B addrs per wave instr)
        float4 hvv[4];
        const float* Hp = HvB + (size_t)h * R_;
        #pragma unroll
        for (int ks = 0; ks < 2; ++ks) {
            const float4* hp4 = (const float4*)(Hp + ks * 32 + quad * 8);
            hvv[2 * ks]     = hp4[0];
            hvv[2 * ks + 1] = hp4[1];
        }

        // A frag = bf16(Ww * Hv), k = quad*8 + i
        bf16x8 afrag[2];
        #pragma unroll
        for (int ks = 0; ks < 2; ++ks) {
            afrag[ks][0] = f2bf(wwf[ks][0].x * hvv[2 * ks].x);
            afrag[ks][1] = f2bf(wwf[ks][0].y * hvv[2 * ks].y);
            afrag[ks][2] = f2bf(wwf[ks][0].z * hvv[2 * ks].z);
            afrag[ks][3] = f2bf(wwf[ks][0].w * hvv[2 * ks].w);
            afrag[ks][4] = f2bf(wwf[ks][1].x * hvv[2 * ks + 1].x);
            afrag[ks][5] = f2bf(wwf[ks][1].y * hvv[2 * ks + 1].y);
            afrag[ks][6] = f2bf(wwf[ks][1].z * hvv[2 * ks + 1].z);
            afrag[ks][7] = f2bf(wwf[ks][1].w * hvv[2 * ks + 1].w);
        }

        f32x4 acc[4];
        #pragma unroll
        for (int ct = 0; ct < 4; ++ct) {
            acc[ct] = (f32x4){0.f, 0.f, 0.f, 0.f};
            acc[ct] = __builtin_amdgcn_mfma_f32_16x16x32_bf16(afrag[0], bfrag[ct][0], acc[ct], 0, 0, 0);
            acc[ct] = __builtin_amdgcn_mfma_f32_16x16x32_bf16(afrag[1], bfrag[ct][1], acc[ct], 0, 0, 0);
        }

        // epilogue: multiply by X, nontemporal float4 store
        size_t pix = (size_t)h * W_ + wbase;
        #pragma unroll
        for (int ct = 0; ct < 4; ++ct) {
            f32x4 o;
            o[0] = acc[ct][0] * xv[cur][ct].x;
            o[1] = acc[ct][1] * xv[cur][ct].y;
            o[2] = acc[ct][2] * xv[cur][ct].z;
            o[3] = acc[ct][3] * xv[cur][ct].w;
            __builtin_nontemporal_store(o, (f32x4*)(Ob + (size_t)(ct * 16 + m) * HW_ + pix));
        }
    }
}

extern "C" void kernel_launch(void* const* d_in, const int* in_sizes, int n_in,
                              void* d_out, int out_size, void* d_ws, size_t ws_size,
                              hipStream_t stream) {
    const float* X  = (const float*)d_in[0];
    const float* p  = (const float*)d_in[1];
    const float* Wc = (const float*)d_in[2];
    const float* bc = (const float*)d_in[3];
    const float* Wh = (const float*)d_in[4];
    const float* bh = (const float*)d_in[5];
    const float* Ww = (const float*)d_in[6];
    const float* bw = (const float*)d_in[7];
    float* out = (float*)d_out;
    float* ws  = (float*)d_ws;

    float* cp  = ws + OFF_CP;
    float* hp  = ws + OFF_HP;
    float* wp  = ws + OFF_WP;
    unsigned short* Mc = (unsigned short*)(ws + OFF_MC);
    float* Hws = ws + OFF_HWS;
    float* Wws = ws + OFF_WWS;

    zero_kernel<<<24, 256, 0, stream>>>(hp, 6144);

    pool_kernel<<<B_ * C_, 256, 0, stream>>>(X, cp, hp, wp);

    affine_all_kernel<<<1792, 256, 0, stream>>>(Wc, bc, Wh, bh, Ww, bw,
                                                cp, hp, wp, p, Mc, Hws, Wws);

    main_kernel<<<1536, 256, 0, stream>>>(X, Mc, Hws, Wws, out);
}

// Round 5
// 332.768 us; speedup vs baseline: 1.0200x; 1.0200x over previous
//
#include <hip/hip_runtime.h>
#include <math.h>

#define B_  16
#define C_  64
#define H_  192
#define W_  192
#define R_  64
#define HW_ (H_*W_)            // 36864
#define HCH 12                 // h rows per main block: 192/12=16 chunks, 16*16*3=768 blocks = 3/CU exact

// ---------------- ws layout (floats) ----------------
#define OFF_CP  0
#define OFF_HP  1024
#define OFF_WP  4096
#define OFF_MC  7168           // Mc stored as bf16: 16*64*64 ushorts fit in 32768 floats of space
#define OFF_HWS 72704
#define OFF_WWS 269312

typedef __attribute__((ext_vector_type(8))) short bf16x8;
typedef __attribute__((ext_vector_type(4))) float f32x4;

static __device__ __forceinline__ short f2bf(float f) {
    unsigned u = __float_as_uint(f);
    unsigned r = u + 0x7fffu + ((u >> 16) & 1u);   // RNE
    return (short)(r >> 16);
}

__global__ __launch_bounds__(256) void zero_kernel(float* p, int n) {
    int i = blockIdx.x * 256 + threadIdx.x;
    if (i < n) p[i] = 0.f;
}

// One block per (b,c). 4 waves; wave wv owns rows [48*wv, 48*wv+48).
// (R1-proven config: float4 loads, unroll 2.)
__global__ __launch_bounds__(256) void pool_kernel(const float* __restrict__ X,
                                                   float* __restrict__ cp,
                                                   float* __restrict__ hp,
                                                   float* __restrict__ wp) {
    int b = blockIdx.x >> 6;
    int c = blockIdx.x & 63;
    int tid = threadIdx.x;
    int wv = tid >> 6, lane = tid & 63;
    int sub = lane >> 4;           // row offset within 4-row group
    int li  = lane & 15;           // position within row
    const float* base = X + (size_t)(b * C_ + c) * HW_ + (size_t)(wv * 48) * W_;

    __shared__ float rowsum[H_];
    __shared__ f32x4 colpart4[4][48];   // [wave][w/4]
    __shared__ float cpart[3];

    f32x4 cacc0 = {0.f,0.f,0.f,0.f}, cacc1 = {0.f,0.f,0.f,0.f}, cacc2 = {0.f,0.f,0.f,0.f};

    #pragma unroll 2
    for (int hh = 0; hh < 48; hh += 4) {
        const float* rp = base + (size_t)(hh + sub) * W_;
        f32x4 x0 = *(const f32x4*)(rp + 4 * li);
        f32x4 x1 = *(const f32x4*)(rp + 4 * (li + 16));
        f32x4 x2 = *(const f32x4*)(rp + 4 * (li + 32));
        cacc0 += x0; cacc1 += x1; cacc2 += x2;
        float s = (x0[0]+x0[1]+x0[2]+x0[3]) + (x1[0]+x1[1]+x1[2]+x1[3])
                + (x2[0]+x2[1]+x2[2]+x2[3]);
        // reduce within the 16-lane group (each group = one row)
        s += __shfl_down(s, 8);
        s += __shfl_down(s, 4);
        s += __shfl_down(s, 2);
        s += __shfl_down(s, 1);
        if (li == 0) rowsum[wv * 48 + hh + sub] = s;
    }
    // reduce col accumulators across the 4 sub-groups (lanes l, l+16, l+32, l+48)
    #pragma unroll
    for (int comp = 0; comp < 4; ++comp) {
        float t0 = cacc0[comp]; t0 += __shfl_down(t0, 16); t0 += __shfl_down(t0, 32); cacc0[comp] = t0;
        float t1 = cacc1[comp]; t1 += __shfl_down(t1, 16); t1 += __shfl_down(t1, 32); cacc1[comp] = t1;
        float t2 = cacc2[comp]; t2 += __shfl_down(t2, 16); t2 += __shfl_down(t2, 32); cacc2[comp] = t2;
    }
    if (lane < 16) {
        colpart4[wv][li]      = cacc0;
        colpart4[wv][li + 16] = cacc1;
        colpart4[wv][li + 32] = cacc2;
    }
    __syncthreads();

    const float inv_cw = 1.0f / 12288.0f;   // 1/(C*W) == 1/(C*H)
    if (tid < 192) {
        const float* cpf = (const float*)colpart4;
        float colv = cpf[tid] + cpf[192 + tid] + cpf[384 + tid] + cpf[576 + tid];
        atomicAdd(&wp[b * W_ + tid], colv * inv_cw);
        float rv = rowsum[tid];
        atomicAdd(&hp[b * H_ + tid], rv * inv_cw);
        float s = rv;
        s += __shfl_down(s, 32);
        s += __shfl_down(s, 16);
        s += __shfl_down(s, 8);
        s += __shfl_down(s, 4);
        s += __shfl_down(s, 2);
        s += __shfl_down(s, 1);
        if ((tid & 63) == 0) cpart[tid >> 6] = s;
    }
    __syncthreads();
    if (tid == 0) cp[b * C_ + c] = (cpart[0] + cpart[1] + cpart[2]) * (1.0f / (float)HW_);
}

// All three affine+sigmoid maps in ONE launch, partitioned by blockIdx:
//   [0,256)      : Mc [b][c][r] = bf16(p[r]*sigmoid(Wc.cp+bc))   D=K=64  (bf16 out)
//   [256,1024)   : Hws[b][h][r] = sigmoid(Wh.hp+bh)              D=K=192
//   [1024,1792)  : Wws[b][w][r] = sigmoid(Ww.wp+bw)              D=K=192
// Mc pre-converted to bf16 (same RNE conversion main_kernel used to do per
// block) -> main loads B-fragments directly; numerically identical (R4 passed).
__global__ __launch_bounds__(256) void affine_all_kernel(
        const float* __restrict__ Wc, const float* __restrict__ bc,
        const float* __restrict__ Wh, const float* __restrict__ bh,
        const float* __restrict__ Ww, const float* __restrict__ bw,
        const float* __restrict__ cp, const float* __restrict__ hp,
        const float* __restrict__ wp, const float* __restrict__ p,
        unsigned short* __restrict__ McBf, float* __restrict__ Hws,
        float* __restrict__ Wws) {
    __shared__ float pl[16 * 193];
    int blk = blockIdx.x;
    const float *Wsrc, *bias, *pool, *pmul;
    float* outp = nullptr;
    bool isMc = false;
    int D, K;
    if (blk < 256) {
        Wsrc = Wc; bias = bc; pool = cp; pmul = p; isMc = true; D = C_; K = C_;
    } else if (blk < 1024) {
        blk -= 256;
        Wsrc = Wh; bias = bh; pool = hp; pmul = nullptr; outp = Hws; D = H_; K = H_;
    } else {
        blk -= 1024;
        Wsrc = Ww; bias = bw; pool = wp; pmul = nullptr; outp = Wws; D = W_; K = W_;
    }

    int tid = threadIdx.x;
    for (int i = tid; i < 16 * K; i += 256) {
        int bb = i / K, kk = i - bb * K;
        pl[bb * (K + 1) + kk] = pool[i];
    }
    __syncthreads();

    int b  = tid & 15;
    int rl = tid >> 4;
    int row = blk * 16 + rl;
    int r = row / D, d = row - r * D;

    const float4* w4 = (const float4*)(Wsrc + (size_t)row * K);
    const float*  pb = &pl[b * (K + 1)];
    float acc = 0.f;
    #pragma unroll 8
    for (int k4 = 0; k4 < (K >> 2); ++k4) {
        float4 wv = w4[k4];
        int k = k4 << 2;
        acc += wv.x * pb[k] + wv.y * pb[k + 1] + wv.z * pb[k + 2] + wv.w * pb[k + 3];
    }
    acc += bias[row];
    float sgm = 1.0f / (1.0f + __expf(-acc));
    if (isMc) {
        sgm *= pmul[r];
        McBf[(size_t)b * (C_ * R_) + (size_t)d * R_ + r] = (unsigned short)f2bf(sgm);
    } else {
        outp[(size_t)b * (D * R_) + (size_t)d * R_ + r] = sgm;
    }
}

// R1-proven structure: one block per (b, 12-row h chunk, 64-wide w strip),
// grid 16*16*3 = 768 = 3/CU exact, depth-1 X prefetch, NO launch-bounds cap
// (R4's cap + HCH=6 regressed). Single change vs R1: B-fragments load directly
// as bf16 (converted upstream) -> prologue is 12 loads, zero cvt.
__global__ __launch_bounds__(256) void main_kernel(const float* __restrict__ X,
                                                   const unsigned short* __restrict__ McBf,
                                                   const float* __restrict__ Hws,
                                                   const float* __restrict__ Wws,
                                                   float* __restrict__ out) {
    int blk = blockIdx.x;
    int b = blk / 48;                  // 16 h-chunks * 3 w-strips
    int rem = blk - b * 48;
    int hc = rem / 3;
    int w0 = (rem - hc * 3) * 64;
    int h0 = hc * HCH;
    int tid = threadIdx.x;
    int wv = tid >> 6, lane = tid & 63;
    int m = lane & 15, quad = lane >> 4;

    const short* McB = (const short*)McBf + (size_t)b * (C_ * R_);
    const float* HvB = Hws + (size_t)b * H_ * R_;
    const float* WwB = Wws + ((size_t)b * W_ + w0) * R_;

    // ---- B fragments: direct bf16 16B loads, once per block ----
    bf16x8 bfrag[4][2];
    #pragma unroll
    for (int ct = 0; ct < 4; ++ct) {
        #pragma unroll
        for (int ks = 0; ks < 2; ++ks)
            bfrag[ct][ks] = *(const bf16x8*)(McB + (size_t)(ct * 16 + m) * R_ + ks * 32 + quad * 8);
    }

    // ---- Ww per-lane weights (A row = w = wv*16+m), fixed across h ----
    float4 wwf[2][2];
    #pragma unroll
    for (int ks = 0; ks < 2; ++ks) {
        const float4* wp4 = (const float4*)(WwB + (size_t)(wv * 16 + m) * R_ + ks * 32 + quad * 8);
        wwf[ks][0] = wp4[0]; wwf[ks][1] = wp4[1];
    }

    int wbase = w0 + wv * 16 + quad * 4;
    const float* Xb = X   + (size_t)b * C_ * HW_;
    float*       Ob = out + (size_t)b * C_ * HW_;

    float4 xv[2][4];
    {   // prologue: prefetch X for h0
        size_t pix0 = (size_t)h0 * W_ + wbase;
        #pragma unroll
        for (int ct = 0; ct < 4; ++ct)
            xv[0][ct] = *(const float4*)(Xb + (size_t)(ct * 16 + m) * HW_ + pix0);
    }

    #pragma unroll
    for (int hi = 0; hi < HCH; ++hi) {
        const int cur = hi & 1;
        const int nxt = cur ^ 1;
        int h = h0 + hi;

        // prefetch X for h+1 first (hides under Hv+cvt+MFMA)
        if (hi + 1 < HCH) {
            size_t pixn = (size_t)(h + 1) * W_ + wbase;
            #pragma unroll
            for (int ct = 0; ct < 4; ++ct)
                xv[nxt][ct] = *(const float4*)(Xb + (size_t)(ct * 16 + m) * HW_ + pixn);
        }

        // Hv for this h (broadcast-ish: 4 distinct 16B addrs per wave instr)
        float4 hvv[4];
        const float* Hp = HvB + (size_t)h * R_;
        #pragma unroll
        for (int ks = 0; ks < 2; ++ks) {
            const float4* hp4 = (const float4*)(Hp + ks * 32 + quad * 8);
            hvv[2 * ks]     = hp4[0];
            hvv[2 * ks + 1] = hp4[1];
        }

        // A frag = bf16(Ww * Hv), k = quad*8 + i
        bf16x8 afrag[2];
        #pragma unroll
        for (int ks = 0; ks < 2; ++ks) {
            afrag[ks][0] = f2bf(wwf[ks][0].x * hvv[2 * ks].x);
            afrag[ks][1] = f2bf(wwf[ks][0].y * hvv[2 * ks].y);
            afrag[ks][2] = f2bf(wwf[ks][0].z * hvv[2 * ks].z);
            afrag[ks][3] = f2bf(wwf[ks][0].w * hvv[2 * ks].w);
            afrag[ks][4] = f2bf(wwf[ks][1].x * hvv[2 * ks + 1].x);
            afrag[ks][5] = f2bf(wwf[ks][1].y * hvv[2 * ks + 1].y);
            afrag[ks][6] = f2bf(wwf[ks][1].z * hvv[2 * ks + 1].z);
            afrag[ks][7] = f2bf(wwf[ks][1].w * hvv[2 * ks + 1].w);
        }

        f32x4 acc[4];
        #pragma unroll
        for (int ct = 0; ct < 4; ++ct) {
            acc[ct] = (f32x4){0.f, 0.f, 0.f, 0.f};
            acc[ct] = __builtin_amdgcn_mfma_f32_16x16x32_bf16(afrag[0], bfrag[ct][0], acc[ct], 0, 0, 0);
            acc[ct] = __builtin_amdgcn_mfma_f32_16x16x32_bf16(afrag[1], bfrag[ct][1], acc[ct], 0, 0, 0);
        }

        // epilogue: multiply by X, nontemporal float4 store
        size_t pix = (size_t)h * W_ + wbase;
        #pragma unroll
        for (int ct = 0; ct < 4; ++ct) {
            f32x4 o;
            o[0] = acc[ct][0] * xv[cur][ct].x;
            o[1] = acc[ct][1] * xv[cur][ct].y;
            o[2] = acc[ct][2] * xv[cur][ct].z;
            o[3] = acc[ct][3] * xv[cur][ct].w;
            __builtin_nontemporal_store(o, (f32x4*)(Ob + (size_t)(ct * 16 + m) * HW_ + pix));
        }
    }
}

extern "C" void kernel_launch(void* const* d_in, const int* in_sizes, int n_in,
                              void* d_out, int out_size, void* d_ws, size_t ws_size,
                              hipStream_t stream) {
    const float* X  = (const float*)d_in[0];
    const float* p  = (const float*)d_in[1];
    const float* Wc = (const float*)d_in[2];
    const float* bc = (const float*)d_in[3];
    const float* Wh = (const float*)d_in[4];
    const float* bh = (const float*)d_in[5];
    const float* Ww = (const float*)d_in[6];
    const float* bw = (const float*)d_in[7];
    float* out = (float*)d_out;
    float* ws  = (float*)d_ws;

    float* cp  = ws + OFF_CP;
    float* hp  = ws + OFF_HP;
    float* wp  = ws + OFF_WP;
    unsigned short* Mc = (unsigned short*)(ws + OFF_MC);
    float* Hws = ws + OFF_HWS;
    float* Wws = ws + OFF_WWS;

    zero_kernel<<<24, 256, 0, stream>>>(hp, 6144);

    pool_kernel<<<B_ * C_, 256, 0, stream>>>(X, cp, hp, wp);

    affine_all_kernel<<<1792, 256, 0, stream>>>(Wc, bc, Wh, bh, Ww, bw,
                                                cp, hp, wp, p, Mc, Hws, Wws);

    main_kernel<<<768, 256, 0, stream>>>(X, Mc, Hws, Wws, out);
}